// Round 1
// baseline (684.638 us; speedup 1.0000x reference)
//
#include <hip/hip_runtime.h>
#include <hip/hip_bf16.h>
#include <math.h>

// ---------------- problem constants ----------------
#define OC     256
#define IC     128
#define HW     56
#define NB     64
#define KK     1152          // IC*9
#define HP     58            // padded spatial
#define PIX    (HW*HW)       // 3136
#define XPAD_ELEMS ((long)NB*HP*HP*IC)   // 27,557,888
#define A_ELEMS    (OC*KK)               // 294,912

typedef __attribute__((ext_vector_type(8))) short  bf16x8;
typedef __attribute__((ext_vector_type(4))) float  f32x4;

__device__ __forceinline__ void async_load16(const void* g, void* l) {
    __builtin_amdgcn_global_load_lds(
        (const __attribute__((address_space(1))) void*)g,
        (__attribute__((address_space(3))) void*)l, 16, 0, 0);
}

// ---------------- kernel 1: weights + BN constants ----------------
// A layout: [oc][kk] with kk = (kh*3+kw)*128 + ic  (K-chunk c reads kk = c*32..c*32+31)
__global__ __launch_bounds__(256) void prep_weights(
        const float* __restrict__ phase, const float* __restrict__ gamma,
        const float* __restrict__ beta,  const float* __restrict__ rmean,
        const float* __restrict__ rvar,
        __hip_bfloat16* __restrict__ ah, __hip_bfloat16* __restrict__ al,
        float* __restrict__ scale, float* __restrict__ bias) {
    int g = blockIdx.x * 256 + threadIdx.x;      // 0 .. 294911
    int oc = g / KK;
    int kk = g - oc * KK;
    int kpos = kk >> 7;          // kh*3+kw
    int ic   = kk & 127;
    int j    = ic * 9 + kpos;    // original flat k = ic*9 + kh*3 + kw
    int pidx = (((oc >> 3) * 144 + (j >> 3)) * 8 + (oc & 7)) * 8 + (j & 7);
    double phi = (double)phase[pidx];
    double c   = cos(phi);
    const double a = 0.987, r = 0.99;
    double num = a*a - 2.0*a*r*c + r*r;
    double den = 1.0 - 2.0*a*r*c + (a*r)*(a*r);
    float t = (float)(num / den);
    __hip_bfloat16 hv = __float2bfloat16(t);
    float hf = __bfloat162float(hv);
    ah[g] = hv;
    al[g] = __float2bfloat16(t - hf);
    if (g < OC) {
        float inv = gamma[g] / sqrtf(rvar[g] + 1e-5f);
        scale[g] = inv;
        bias[g]  = beta[g] - rmean[g] * inv;
    }
}

// ---------------- kernel 2: pad + transpose + bf16 hi/lo split ----------------
// x: [64][128][56][56] f32  ->  xh/xl: [64][58][58][128] bf16 (channels-last, zero border)
__global__ __launch_bounds__(256) void prep_x(
        const float* __restrict__ x,
        __hip_bfloat16* __restrict__ xh, __hip_bfloat16* __restrict__ xl) {
    int hp  = blockIdx.x;    // 0..57
    int img = blockIdx.y;    // 0..63
    __shared__ float tile[IC * 57];   // [ic][w], stride 57 to dodge bank conflicts
    bool border = (hp == 0) || (hp == HP - 1);
    int t = threadIdx.x;
    if (!border) {
        int h = hp - 1;
        for (int it = 0; it < 28; ++it) {        // 128*56/256
            int idx = it * 256 + t;
            int ic  = idx / HW;
            int w   = idx - ic * HW;
            tile[ic * 57 + w] = x[(((long)img * IC + ic) * HW + h) * HW + w];
        }
    }
    __syncthreads();
    long base = ((long)(img * HP + hp)) * HP * IC;
    for (int it = 0; it < 29; ++it) {            // 58*128/256
        int idx = it * 256 + t;
        int wp = idx >> 7;
        int ic = idx & 127;
        float v = 0.f;
        if (!border && wp >= 1 && wp <= HW) v = tile[ic * 57 + (wp - 1)];
        __hip_bfloat16 hv = __float2bfloat16(v);
        float hf = __bfloat162float(hv);
        xh[base + idx] = hv;
        xl[base + idx] = __float2bfloat16(v - hf);
    }
}

// ---------------- kernel 3: implicit GEMM conv + BN + ReLU6 ----------------
// C[oc][pix] = sum_k A[oc][k] * B[k][pix];  K order = (kh,kw,ic), 36 chunks of 32.
// Block: 128 oc x 128 pixels; 4 waves each 64x64 (4x4 frags of 16x16x32).
// 3-MFMA bf16 split per product: hi*hi + hi*lo + lo*hi (shared fp32 accumulator).
__global__ __launch_bounds__(256) void conv_gemm(
        const __hip_bfloat16* __restrict__ ah, const __hip_bfloat16* __restrict__ al,
        const __hip_bfloat16* __restrict__ xh, const __hip_bfloat16* __restrict__ xl,
        const float* __restrict__ scale, const float* __restrict__ bias,
        float* __restrict__ out) {
    __shared__ __hip_bfloat16 sAh[128 * 32];
    __shared__ __hip_bfloat16 sAl[128 * 32];
    __shared__ __hip_bfloat16 sBh[128 * 32];
    __shared__ __hip_bfloat16 sBl[128 * 32];

    int bid = blockIdx.x;
    int img = bid / 50;
    int rem = bid - img * 50;
    int mt  = rem >> 1;      // 0..24  pixel tile
    int ot  = rem & 1;       // oc tile

    int t    = threadIdx.x;
    int lane = t & 63;
    int wave = t >> 6;
    int wm   = wave & 1;     // oc half (64)
    int wn   = wave >> 1;    // pixel half (64)

    // staging map: issue j in {0,1}: elem e=(j*256+t)*8, row=e/32, col=e%32
    int row0 = t >> 2;            // rows 0..63 (j=0), +64 for j=1
    int col0 = (t & 3) * 8;

    // A global offsets (K is linear: chunk c -> kk base c*32)
    long aoff0 = (long)(ot * 128 + row0) * KK + col0;
    long aoff1 = (long)(ot * 128 + row0 + 64) * KK + col0;

    // B pixel coords for this thread's two staging rows (clamp dead pixels)
    int m0 = mt * 128 + row0;      if (m0 > PIX - 1) m0 = PIX - 1;
    int m1 = mt * 128 + row0 + 64; if (m1 > PIX - 1) m1 = PIX - 1;
    int h0 = m0 / HW, w0 = m0 - h0 * HW;
    int h1 = m1 / HW, w1 = m1 - h1 * HW;
    int pixBase0 = (img * HP + h0) * HP + w0;   // padded-flat, before (kh,kw) shift
    int pixBase1 = (img * HP + h1) * HP + w1;

    f32x4 acc[4][4];
#pragma unroll
    for (int i = 0; i < 4; ++i)
#pragma unroll
        for (int jj = 0; jj < 4; ++jj) acc[i][jj] = (f32x4){0.f, 0.f, 0.f, 0.f};

    for (int c = 0; c < 36; ++c) {
        int kq = c >> 2;            // kh*3+kw
        int kh = kq / 3;
        int kw = kq - kh * 3;
        int icb = (c & 3) << 5;
        int sh = kh * HP + kw;
        long b0 = (long)(pixBase0 + sh) * IC + icb + col0;
        long b1 = (long)(pixBase1 + sh) * IC + icb + col0;
        long ao = (long)c * 32;

        async_load16(ah + aoff0 + ao, &sAh[t * 8]);
        async_load16(ah + aoff1 + ao, &sAh[2048 + t * 8]);
        async_load16(al + aoff0 + ao, &sAl[t * 8]);
        async_load16(al + aoff1 + ao, &sAl[2048 + t * 8]);
        async_load16(xh + b0, &sBh[t * 8]);
        async_load16(xh + b1, &sBh[2048 + t * 8]);
        async_load16(xl + b0, &sBl[t * 8]);
        async_load16(xl + b1, &sBl[2048 + t * 8]);

        __syncthreads();

        bf16x8 aH[4], aL[4], bH[4], bL[4];
#pragma unroll
        for (int f = 0; f < 4; ++f) {
            int aoff = (wm * 64 + f * 16 + (lane & 15)) * 32 + ((lane >> 4) << 3);
            aH[f] = *(const bf16x8*)&sAh[aoff];
            aL[f] = *(const bf16x8*)&sAl[aoff];
            int boff = (wn * 64 + f * 16 + (lane & 15)) * 32 + ((lane >> 4) << 3);
            bH[f] = *(const bf16x8*)&sBh[boff];
            bL[f] = *(const bf16x8*)&sBl[boff];
        }
#pragma unroll
        for (int fm = 0; fm < 4; ++fm)
#pragma unroll
            for (int fn = 0; fn < 4; ++fn) {
                acc[fm][fn] = __builtin_amdgcn_mfma_f32_16x16x32_bf16(aL[fm], bH[fn], acc[fm][fn], 0, 0, 0);
                acc[fm][fn] = __builtin_amdgcn_mfma_f32_16x16x32_bf16(aH[fm], bL[fn], acc[fm][fn], 0, 0, 0);
                acc[fm][fn] = __builtin_amdgcn_mfma_f32_16x16x32_bf16(aH[fm], bH[fn], acc[fm][fn], 0, 0, 0);
            }
        __syncthreads();
    }

    // epilogue: BN (eval) + ReLU6, store fp32
    int pixc = mt * 128 + wn * 64 + (lane & 15);
    int occ0 = ot * 128 + wm * 64 + ((lane >> 4) << 2);
#pragma unroll
    for (int fm = 0; fm < 4; ++fm) {
#pragma unroll
        for (int r = 0; r < 4; ++r) {
            int oc = occ0 + fm * 16 + r;
            float sc = scale[oc], bi = bias[oc];
            long obase = ((long)(img * OC + oc)) * PIX;
#pragma unroll
            for (int fn = 0; fn < 4; ++fn) {
                int pix = pixc + fn * 16;
                if (pix < PIX) {
                    float v = acc[fm][fn][r] * sc + bi;
                    v = fminf(fmaxf(v, 0.f), 6.f);
                    out[obase + pix] = v;
                }
            }
        }
    }
}

// ---------------- launch ----------------
extern "C" void kernel_launch(void* const* d_in, const int* in_sizes, int n_in,
                              void* d_out, int out_size, void* d_ws, size_t ws_size,
                              hipStream_t stream) {
    const float* x     = (const float*)d_in[0];
    const float* phase = (const float*)d_in[1];
    const float* gamma = (const float*)d_in[2];
    const float* beta  = (const float*)d_in[3];
    const float* rmean = (const float*)d_in[4];
    const float* rvar  = (const float*)d_in[5];
    float* out = (float*)d_out;

    // workspace layout (~111.5 MB total)
    __hip_bfloat16* xh = (__hip_bfloat16*)d_ws;
    __hip_bfloat16* xl = xh + XPAD_ELEMS;
    __hip_bfloat16* ah = xl + XPAD_ELEMS;
    __hip_bfloat16* al = ah + A_ELEMS;
    float* scale = (float*)(al + A_ELEMS);
    float* bias  = scale + OC;

    prep_weights<<<A_ELEMS / 256, 256, 0, stream>>>(phase, gamma, beta, rmean, rvar,
                                                    ah, al, scale, bias);
    prep_x<<<dim3(HP, NB), 256, 0, stream>>>(x, xh, xl);
    conv_gemm<<<NB * 50, 256, 0, stream>>>(ah, al, xh, xl, scale, bias, out);
}

// Round 2
// 668.803 us; speedup vs baseline: 1.0237x; 1.0237x over previous
//
#include <hip/hip_runtime.h>
#include <hip/hip_bf16.h>
#include <math.h>

// ---------------- problem constants ----------------
#define OC     256
#define IC     128
#define HW     56
#define NB     64
#define KK     1152          // IC*9
#define HP     58            // padded spatial
#define PIX    (HW*HW)       // 3136
#define XPAD_ELEMS ((long)NB*HP*HP*IC)   // 27,557,888
#define A_ELEMS    (OC*KK)               // 294,912

typedef __attribute__((ext_vector_type(8))) short          bf16x8;
typedef __attribute__((ext_vector_type(8))) unsigned short u16x8;
typedef __attribute__((ext_vector_type(4))) float          f32x4;

__device__ __forceinline__ void async_load16(const void* g, void* l) {
    __builtin_amdgcn_global_load_lds(
        (const __attribute__((address_space(1))) void*)g,
        (__attribute__((address_space(3))) void*)l, 16, 0, 0);
}

// bf16 RNE convert (manual, no NaN path needed for our data)
__device__ __forceinline__ unsigned short f2bf(float f) {
    unsigned int u = __float_as_uint(f);
    return (unsigned short)((u + 0x7fffu + ((u >> 16) & 1u)) >> 16);
}
__device__ __forceinline__ float bf2f(unsigned short b) {
    return __uint_as_float(((unsigned int)b) << 16);
}

// XOR-swizzled LDS element offset for logical (row, colgroup q in 0..3).
// Physical slot = q ^ ((row>>1)&3): 16 lanes of a quad hit all 32 banks 2-way.
__device__ __forceinline__ int lds_off(int row, int q) {
    return row * 32 + (((q ^ (row >> 1)) & 3) << 3);
}

// ---------------- kernel 1: weights + BN constants ----------------
// A layout: [oc][kk] with kk = (kh*3+kw)*128 + ic  (K-chunk c reads kk = c*32..c*32+31)
__global__ __launch_bounds__(256) void prep_weights(
        const float* __restrict__ phase, const float* __restrict__ gamma,
        const float* __restrict__ beta,  const float* __restrict__ rmean,
        const float* __restrict__ rvar,
        __hip_bfloat16* __restrict__ ah, __hip_bfloat16* __restrict__ al,
        float* __restrict__ scale, float* __restrict__ bias) {
    int g = blockIdx.x * 256 + threadIdx.x;      // 0 .. 294911
    int oc = g / KK;
    int kk = g - oc * KK;
    int kpos = kk >> 7;          // kh*3+kw
    int ic   = kk & 127;
    int j    = ic * 9 + kpos;    // original flat k = ic*9 + kh*3 + kw
    int pidx = (((oc >> 3) * 144 + (j >> 3)) * 8 + (oc & 7)) * 8 + (j & 7);
    double phi = (double)phase[pidx];
    double c   = cos(phi);
    const double a = 0.987, r = 0.99;
    double num = a*a - 2.0*a*r*c + r*r;
    double den = 1.0 - 2.0*a*r*c + (a*r)*(a*r);
    float t = (float)(num / den);
    unsigned short hb = f2bf(t);
    float hf = bf2f(hb);
    ((unsigned short*)ah)[g] = hb;
    ((unsigned short*)al)[g] = f2bf(t - hf);
    if (g < OC) {
        float inv = gamma[g] / sqrtf(rvar[g] + 1e-5f);
        scale[g] = inv;
        bias[g]  = beta[g] - rmean[g] * inv;
    }
}

// ---------------- kernel 2: pad + transpose + bf16 hi/lo split ----------------
// x: [64][128][56][56] f32 -> xh/xl: [64][58][58][128] bf16 (channels-last, zero border)
__global__ __launch_bounds__(256) void prep_x(
        const float* __restrict__ x,
        __hip_bfloat16* __restrict__ xh, __hip_bfloat16* __restrict__ xl) {
    int hp  = blockIdx.x;    // 0..57
    int img = blockIdx.y;    // 0..63
    __shared__ float tile[IC * 57];   // [ic][w], stride 57
    int t = threadIdx.x;
    bool border = (hp == 0) || (hp == HP - 1);
    if (!border) {
        int h = hp - 1;
        const float* src = x + (long)img * IC * PIX + h * HW;
#pragma unroll
        for (int i = 0; i < 7; ++i) {            // 128*14 float4 = 1792
            int idx = i * 256 + t;
            int ic  = idx / 14;
            int w4  = (idx - ic * 14) * 4;
            float4 v = *(const float4*)&src[(long)ic * PIX + w4];
            tile[ic * 57 + w4 + 0] = v.x;
            tile[ic * 57 + w4 + 1] = v.y;
            tile[ic * 57 + w4 + 2] = v.z;
            tile[ic * 57 + w4 + 3] = v.w;
        }
    }
    __syncthreads();
    long base = ((long)(img * HP + hp)) * HP * IC;
#pragma unroll
    for (int i = 0; i < 4; ++i) {                // 58*16 = 928 vec-tasks
        int v = i * 256 + t;
        if (v < 928) {
            int icg = v & 15;                    // 8 ic per task
            int wp  = v >> 4;                    // 0..57
            bool inw = !border && wp >= 1 && wp <= HW;
            u16x8 hv, lv;
#pragma unroll
            for (int j = 0; j < 8; ++j) {
                float f = inw ? tile[(icg * 8 + j) * 57 + (wp - 1)] : 0.f;
                unsigned short hb = f2bf(f);
                hv[j] = hb;
                lv[j] = f2bf(f - bf2f(hb));
            }
            long o = base + wp * IC + icg * 8;
            *(u16x8*)&((unsigned short*)xh)[o] = hv;
            *(u16x8*)&((unsigned short*)xl)[o] = lv;
        }
    }
}

// ---------------- kernel 3: implicit GEMM conv + BN + ReLU6 ----------------
// C[oc][pix] = sum_k A[oc][k] * B[k][pix];  K order = (kh,kw,ic), 36 chunks of 32.
// Block: 128 oc x 128 pixels; 4 waves each 64x64 (4x4 frags of 16x16x32).
// 3-MFMA bf16 split: aL*bH + aH*bL + aH*bH into one fp32 accumulator.
// LDS tiles XOR-swizzled (lds_off) to kill the 8-way bank conflict.
__global__ __launch_bounds__(256) void conv_gemm(
        const __hip_bfloat16* __restrict__ ah, const __hip_bfloat16* __restrict__ al,
        const __hip_bfloat16* __restrict__ xh, const __hip_bfloat16* __restrict__ xl,
        const float* __restrict__ scale, const float* __restrict__ bias,
        float* __restrict__ out) {
    __shared__ __hip_bfloat16 sAh[128 * 32];
    __shared__ __hip_bfloat16 sAl[128 * 32];
    __shared__ __hip_bfloat16 sBh[128 * 32];
    __shared__ __hip_bfloat16 sBl[128 * 32];

    int bid = blockIdx.x;
    int img = bid / 50;
    int rem = bid - img * 50;
    int mt  = rem >> 1;      // 0..24  pixel tile
    int ot  = rem & 1;       // oc tile

    int t    = threadIdx.x;
    int lane = t & 63;
    int wave = t >> 6;
    int wm   = wave & 1;     // oc half (64)
    int wn   = wave >> 1;    // pixel half (64)

    // staging map with swizzle: thread t stages physical slot (t&3) of row t>>2,
    // which holds logical colgroup (t&3) ^ ((t>>3)&3)
    int row0 = t >> 2;                           // rows 0..63 (j=0), +64 for j=1
    int col0 = (((t & 3) ^ ((t >> 3) & 3))) << 3;

    // A global offsets (K linear: chunk c -> kk base c*32)
    long aoff0 = (long)(ot * 128 + row0) * KK + col0;
    long aoff1 = (long)(ot * 128 + row0 + 64) * KK + col0;

    // B pixel coords for this thread's two staging rows (clamp dead pixels)
    int m0 = mt * 128 + row0;      if (m0 > PIX - 1) m0 = PIX - 1;
    int m1 = mt * 128 + row0 + 64; if (m1 > PIX - 1) m1 = PIX - 1;
    int h0 = m0 / HW, w0 = m0 - h0 * HW;
    int h1 = m1 / HW, w1 = m1 - h1 * HW;
    int pixBase0 = (img * HP + h0) * HP + w0;
    int pixBase1 = (img * HP + h1) * HP + w1;

    // fragment LDS offsets (loop-invariant)
    int ar[4], br[4];
#pragma unroll
    for (int f = 0; f < 4; ++f) {
        ar[f] = lds_off(wm * 64 + f * 16 + (lane & 15), lane >> 4);
        br[f] = lds_off(wn * 64 + f * 16 + (lane & 15), lane >> 4);
    }

    f32x4 acc[4][4];
#pragma unroll
    for (int i = 0; i < 4; ++i)
#pragma unroll
        for (int jj = 0; jj < 4; ++jj) acc[i][jj] = (f32x4){0.f, 0.f, 0.f, 0.f};

    for (int c = 0; c < 36; ++c) {
        int kq = c >> 2;            // kh*3+kw
        int kh = kq / 3;
        int kw = kq - kh * 3;
        int icb = (c & 3) << 5;
        int sh = kh * HP + kw;
        long b0 = (long)(pixBase0 + sh) * IC + icb + col0;
        long b1 = (long)(pixBase1 + sh) * IC + icb + col0;
        long ao = (long)c * 32;

        async_load16(ah + aoff0 + ao, &sAh[t * 8]);
        async_load16(ah + aoff1 + ao, &sAh[2048 + t * 8]);
        async_load16(al + aoff0 + ao, &sAl[t * 8]);
        async_load16(al + aoff1 + ao, &sAl[2048 + t * 8]);
        async_load16(xh + b0, &sBh[t * 8]);
        async_load16(xh + b1, &sBh[2048 + t * 8]);
        async_load16(xl + b0, &sBl[t * 8]);
        async_load16(xl + b1, &sBl[2048 + t * 8]);

        __syncthreads();

        bf16x8 aH[4], aL[4], bH[4], bL[4];
#pragma unroll
        for (int f = 0; f < 4; ++f) {
            aH[f] = *(const bf16x8*)&sAh[ar[f]];
            aL[f] = *(const bf16x8*)&sAl[ar[f]];
            bH[f] = *(const bf16x8*)&sBh[br[f]];
            bL[f] = *(const bf16x8*)&sBl[br[f]];
        }
#pragma unroll
        for (int fm = 0; fm < 4; ++fm)
#pragma unroll
            for (int fn = 0; fn < 4; ++fn) {
                acc[fm][fn] = __builtin_amdgcn_mfma_f32_16x16x32_bf16(aL[fm], bH[fn], acc[fm][fn], 0, 0, 0);
                acc[fm][fn] = __builtin_amdgcn_mfma_f32_16x16x32_bf16(aH[fm], bL[fn], acc[fm][fn], 0, 0, 0);
                acc[fm][fn] = __builtin_amdgcn_mfma_f32_16x16x32_bf16(aH[fm], bH[fn], acc[fm][fn], 0, 0, 0);
            }
        __syncthreads();
    }

    // epilogue: BN (eval) + ReLU6, store fp32
    int pixc = mt * 128 + wn * 64 + (lane & 15);
    int occ0 = ot * 128 + wm * 64 + ((lane >> 4) << 2);
#pragma unroll
    for (int fm = 0; fm < 4; ++fm) {
#pragma unroll
        for (int r = 0; r < 4; ++r) {
            int oc = occ0 + fm * 16 + r;
            float sc = scale[oc], bi = bias[oc];
            long obase = ((long)(img * OC + oc)) * PIX;
#pragma unroll
            for (int fn = 0; fn < 4; ++fn) {
                int pix = pixc + fn * 16;
                if (pix < PIX) {
                    float v = acc[fm][fn][r] * sc + bi;
                    v = fminf(fmaxf(v, 0.f), 6.f);
                    out[obase + pix] = v;
                }
            }
        }
    }
}

// ---------------- launch ----------------
extern "C" void kernel_launch(void* const* d_in, const int* in_sizes, int n_in,
                              void* d_out, int out_size, void* d_ws, size_t ws_size,
                              hipStream_t stream) {
    const float* x     = (const float*)d_in[0];
    const float* phase = (const float*)d_in[1];
    const float* gamma = (const float*)d_in[2];
    const float* beta  = (const float*)d_in[3];
    const float* rmean = (const float*)d_in[4];
    const float* rvar  = (const float*)d_in[5];
    float* out = (float*)d_out;

    __hip_bfloat16* xh = (__hip_bfloat16*)d_ws;
    __hip_bfloat16* xl = xh + XPAD_ELEMS;
    __hip_bfloat16* ah = xl + XPAD_ELEMS;
    __hip_bfloat16* al = ah + A_ELEMS;
    float* scale = (float*)(al + A_ELEMS);
    float* bias  = scale + OC;

    prep_weights<<<A_ELEMS / 256, 256, 0, stream>>>(phase, gamma, beta, rmean, rvar,
                                                    ah, al, scale, bias);
    prep_x<<<dim3(HP, NB), 256, 0, stream>>>(x, xh, xl);
    conv_gemm<<<NB * 50, 256, 0, stream>>>(ah, al, xh, xl, scale, bias, out);
}

// Round 3
// 617.759 us; speedup vs baseline: 1.1083x; 1.0826x over previous
//
#include <hip/hip_runtime.h>
#include <hip/hip_bf16.h>
#include <math.h>

// ---------------- problem constants ----------------
#define OC     256
#define IC     128
#define HW     56
#define NB     64
#define KK     1152          // IC*9
#define HP     58            // padded spatial
#define PIX    (HW*HW)       // 3136
#define XPAD_ELEMS ((long)NB*HP*HP*IC)   // 27,557,888
#define A_ELEMS    (OC*KK)               // 294,912

typedef __attribute__((ext_vector_type(8))) short          bf16x8;
typedef __attribute__((ext_vector_type(8))) unsigned short u16x8;
typedef __attribute__((ext_vector_type(4))) float          f32x4;

__device__ __forceinline__ void async_load16(const void* g, void* l) {
    __builtin_amdgcn_global_load_lds(
        (const __attribute__((address_space(1))) void*)g,
        (__attribute__((address_space(3))) void*)l, 16, 0, 0);
}

// bf16 RNE convert (manual, no NaN path needed for our data)
__device__ __forceinline__ unsigned short f2bf(float f) {
    unsigned int u = __float_as_uint(f);
    return (unsigned short)((u + 0x7fffu + ((u >> 16) & 1u)) >> 16);
}
__device__ __forceinline__ float bf2f(unsigned short b) {
    return __uint_as_float(((unsigned int)b) << 16);
}

// XOR-swizzled LDS element offset for logical (row, colgroup q in 0..3):
// physical slot = q ^ ((row>>1)&3) -> 2-way bank aliasing only (free, m136).
__device__ __forceinline__ int lds_off(int row, int q) {
    return row * 32 + (((q ^ (row >> 1)) & 3) << 3);
}

// ---------------- kernel 1: weights + BN constants ----------------
// A layout: [oc][kk], kk = (kh*3+kw)*128 + ic  (K-chunk c reads kk = c*32..c*32+31)
__global__ __launch_bounds__(256) void prep_weights(
        const float* __restrict__ phase, const float* __restrict__ gamma,
        const float* __restrict__ beta,  const float* __restrict__ rmean,
        const float* __restrict__ rvar,
        __hip_bfloat16* __restrict__ ah, __hip_bfloat16* __restrict__ al,
        float* __restrict__ scale, float* __restrict__ bias) {
    int g = blockIdx.x * 256 + threadIdx.x;      // 0 .. 294911
    int oc = g / KK;
    int kk = g - oc * KK;
    int kpos = kk >> 7;          // kh*3+kw
    int ic   = kk & 127;
    int j    = ic * 9 + kpos;    // original flat k = ic*9 + kh*3 + kw
    int pidx = (((oc >> 3) * 144 + (j >> 3)) * 8 + (oc & 7)) * 8 + (j & 7);
    double phi = (double)phase[pidx];
    double c   = cos(phi);
    const double a = 0.987, r = 0.99;
    double num = a*a - 2.0*a*r*c + r*r;
    double den = 1.0 - 2.0*a*r*c + (a*r)*(a*r);
    float t = (float)(num / den);
    unsigned short hb = f2bf(t);
    float hf = bf2f(hb);
    ((unsigned short*)ah)[g] = hb;
    ((unsigned short*)al)[g] = f2bf(t - hf);
    if (g < OC) {
        float inv = gamma[g] / sqrtf(rvar[g] + 1e-5f);
        scale[g] = inv;
        bias[g]  = beta[g] - rmean[g] * inv;
    }
}

// ---------------- kernel 2: pad + transpose + bf16 hi/lo split ----------------
// x: [64][128][56][56] f32 -> xh/xl: [64][58][58][128] bf16 (channels-last, zero border)
__global__ __launch_bounds__(256) void prep_x(
        const float* __restrict__ x,
        __hip_bfloat16* __restrict__ xh, __hip_bfloat16* __restrict__ xl) {
    int hp  = blockIdx.x;    // 0..57
    int img = blockIdx.y;    // 0..63
    __shared__ float tile[IC * 57];   // [ic][w], stride 57
    int t = threadIdx.x;
    bool border = (hp == 0) || (hp == HP - 1);
    if (!border) {
        int h = hp - 1;
        const float* src = x + (long)img * IC * PIX + h * HW;
#pragma unroll
        for (int i = 0; i < 7; ++i) {            // 128*14 float4 = 1792
            int idx = i * 256 + t;
            int ic  = idx / 14;
            int w4  = (idx - ic * 14) * 4;
            float4 v = *(const float4*)&src[(long)ic * PIX + w4];
            tile[ic * 57 + w4 + 0] = v.x;
            tile[ic * 57 + w4 + 1] = v.y;
            tile[ic * 57 + w4 + 2] = v.z;
            tile[ic * 57 + w4 + 3] = v.w;
        }
    }
    __syncthreads();
    long base = ((long)(img * HP + hp)) * HP * IC;
#pragma unroll
    for (int i = 0; i < 4; ++i) {                // 58*16 = 928 vec-tasks
        int v = i * 256 + t;
        if (v < 928) {
            int icg = v & 15;                    // 8 ic per task
            int wp  = v >> 4;                    // 0..57
            bool inw = !border && wp >= 1 && wp <= HW;
            u16x8 hv, lv;
#pragma unroll
            for (int j = 0; j < 8; ++j) {
                float f = inw ? tile[(icg * 8 + j) * 57 + (wp - 1)] : 0.f;
                unsigned short hb = f2bf(f);
                hv[j] = hb;
                lv[j] = f2bf(f - bf2f(hb));
            }
            long o = base + wp * IC + icg * 8;
            *(u16x8*)&((unsigned short*)xh)[o] = hv;
            *(u16x8*)&((unsigned short*)xl)[o] = lv;
        }
    }
}

// ---------------- kernel 3: implicit GEMM conv + BN + ReLU6 ----------------
// Double-buffered single-barrier pipeline:
//   sync -> issue prefetch(c+1) into other buffer -> compute(c)
// B K-offset closed form: bshift(c) = 32*c + 7040*(c>=12) + 7040*(c>=24)
__global__ __launch_bounds__(256) void conv_gemm(
        const __hip_bfloat16* __restrict__ ah, const __hip_bfloat16* __restrict__ al,
        const __hip_bfloat16* __restrict__ xh, const __hip_bfloat16* __restrict__ xl,
        const float* __restrict__ scale, const float* __restrict__ bias,
        float* __restrict__ out) {
    __shared__ __hip_bfloat16 sAh0[4096], sAl0[4096], sBh0[4096], sBl0[4096];
    __shared__ __hip_bfloat16 sAh1[4096], sAl1[4096], sBh1[4096], sBl1[4096];

    int bid = blockIdx.x;
    int img = bid / 50;
    int rem = bid - img * 50;
    int mt  = rem >> 1;      // 0..24  pixel tile
    int ot  = rem & 1;       // oc tile

    int t    = threadIdx.x;
    int lane = t & 63;
    int wave = t >> 6;
    int wm   = wave & 1;     // oc half (64)
    int wn   = wave >> 1;    // pixel half (64)

    // staging map with swizzle: thread t stages physical slot (t&3) of row t>>2,
    // which holds logical colgroup (t&3) ^ ((t>>3)&3)
    int row0 = t >> 2;
    int col0 = (((t & 3) ^ ((t >> 3) & 3))) << 3;

    // thread-constant global base pointers
    const __hip_bfloat16* pah0 = ah + (long)(ot * 128 + row0) * KK + col0;
    const __hip_bfloat16* pah1 = pah0 + (long)64 * KK;
    const __hip_bfloat16* pal0 = al + (long)(ot * 128 + row0) * KK + col0;
    const __hip_bfloat16* pal1 = pal0 + (long)64 * KK;

    int m0 = mt * 128 + row0;      if (m0 > PIX - 1) m0 = PIX - 1;
    int m1 = mt * 128 + row0 + 64; if (m1 > PIX - 1) m1 = PIX - 1;
    int h0 = m0 / HW, w0 = m0 - h0 * HW;
    int h1 = m1 / HW, w1 = m1 - h1 * HW;
    const __hip_bfloat16* pxh0 = xh + (long)((img * HP + h0) * HP + w0) * IC + col0;
    const __hip_bfloat16* pxh1 = xh + (long)((img * HP + h1) * HP + w1) * IC + col0;
    const __hip_bfloat16* pxl0 = xl + (long)((img * HP + h0) * HP + w0) * IC + col0;
    const __hip_bfloat16* pxl1 = xl + (long)((img * HP + h1) * HP + w1) * IC + col0;

    // fragment LDS offsets (loop-invariant, shared by both buffers)
    int ar[4], br[4];
#pragma unroll
    for (int f = 0; f < 4; ++f) {
        ar[f] = lds_off(wm * 64 + f * 16 + (lane & 15), lane >> 4);
        br[f] = lds_off(wn * 64 + f * 16 + (lane & 15), lane >> 4);
    }

    f32x4 acc[4][4];
#pragma unroll
    for (int i = 0; i < 4; ++i)
#pragma unroll
        for (int jj = 0; jj < 4; ++jj) acc[i][jj] = (f32x4){0.f, 0.f, 0.f, 0.f};

#define ISSUE(ci, SAH, SAL, SBH, SBL)                                          \
    {                                                                           \
        int bs = 32 * (ci) + ((ci) >= 12 ? 7040 : 0) + ((ci) >= 24 ? 7040 : 0); \
        long a0 = (long)(ci) * 32;                                              \
        async_load16(pah0 + a0, &SAH[t * 8]);                                   \
        async_load16(pah1 + a0, &SAH[2048 + t * 8]);                            \
        async_load16(pal0 + a0, &SAL[t * 8]);                                   \
        async_load16(pal1 + a0, &SAL[2048 + t * 8]);                            \
        async_load16(pxh0 + bs, &SBH[t * 8]);                                   \
        async_load16(pxh1 + bs, &SBH[2048 + t * 8]);                            \
        async_load16(pxl0 + bs, &SBL[t * 8]);                                   \
        async_load16(pxl1 + bs, &SBL[2048 + t * 8]);                            \
    }

#define COMPUTE(SAH, SAL, SBH, SBL)                                             \
    {                                                                           \
        bf16x8 aH[4], aL[4], bH[4], bL[4];                                      \
        _Pragma("unroll")                                                       \
        for (int f = 0; f < 4; ++f) {                                           \
            aH[f] = *(const bf16x8*)&SAH[ar[f]];                                \
            aL[f] = *(const bf16x8*)&SAL[ar[f]];                                \
            bH[f] = *(const bf16x8*)&SBH[br[f]];                                \
            bL[f] = *(const bf16x8*)&SBL[br[f]];                                \
        }                                                                       \
        _Pragma("unroll")                                                       \
        for (int fm = 0; fm < 4; ++fm)                                          \
            _Pragma("unroll")                                                   \
            for (int fn = 0; fn < 4; ++fn) {                                    \
                acc[fm][fn] = __builtin_amdgcn_mfma_f32_16x16x32_bf16(aL[fm], bH[fn], acc[fm][fn], 0, 0, 0); \
                acc[fm][fn] = __builtin_amdgcn_mfma_f32_16x16x32_bf16(aH[fm], bL[fn], acc[fm][fn], 0, 0, 0); \
                acc[fm][fn] = __builtin_amdgcn_mfma_f32_16x16x32_bf16(aH[fm], bH[fn], acc[fm][fn], 0, 0, 0); \
            }                                                                   \
    }

    ISSUE(0, sAh0, sAl0, sBh0, sBl0);
#pragma unroll 1
    for (int cc = 0; cc < 18; ++cc) {
        int c = cc * 2;
        __syncthreads();                               // drains prefetch for c
        ISSUE(c + 1, sAh1, sAl1, sBh1, sBl1);          // prefetch next (c+1<36 always)
        COMPUTE(sAh0, sAl0, sBh0, sBl0);               // consume c
        __syncthreads();                               // drains prefetch for c+1
        if (c + 2 < 36) ISSUE(c + 2, sAh0, sAl0, sBh0, sBl0);
        COMPUTE(sAh1, sAl1, sBh1, sBl1);               // consume c+1
    }
#undef ISSUE
#undef COMPUTE

    // epilogue: BN (eval) + ReLU6, store fp32
    int pixc = mt * 128 + wn * 64 + (lane & 15);
    int occ0 = ot * 128 + wm * 64 + ((lane >> 4) << 2);
#pragma unroll
    for (int fm = 0; fm < 4; ++fm) {
#pragma unroll
        for (int r = 0; r < 4; ++r) {
            int oc = occ0 + fm * 16 + r;
            float sc = scale[oc], bi = bias[oc];
            long obase = ((long)(img * OC + oc)) * PIX;
#pragma unroll
            for (int fn = 0; fn < 4; ++fn) {
                int pix = pixc + fn * 16;
                if (pix < PIX) {
                    float v = acc[fm][fn][r] * sc + bi;
                    v = fminf(fmaxf(v, 0.f), 6.f);
                    out[obase + pix] = v;
                }
            }
        }
    }
}

// ---------------- launch ----------------
extern "C" void kernel_launch(void* const* d_in, const int* in_sizes, int n_in,
                              void* d_out, int out_size, void* d_ws, size_t ws_size,
                              hipStream_t stream) {
    const float* x     = (const float*)d_in[0];
    const float* phase = (const float*)d_in[1];
    const float* gamma = (const float*)d_in[2];
    const float* beta  = (const float*)d_in[3];
    const float* rmean = (const float*)d_in[4];
    const float* rvar  = (const float*)d_in[5];
    float* out = (float*)d_out;

    __hip_bfloat16* xh = (__hip_bfloat16*)d_ws;
    __hip_bfloat16* xl = xh + XPAD_ELEMS;
    __hip_bfloat16* ah = xl + XPAD_ELEMS;
    __hip_bfloat16* al = ah + A_ELEMS;
    float* scale = (float*)(al + A_ELEMS);
    float* bias  = scale + OC;

    prep_weights<<<A_ELEMS / 256, 256, 0, stream>>>(phase, gamma, beta, rmean, rvar,
                                                    ah, al, scale, bias);
    prep_x<<<dim3(HP, NB), 256, 0, stream>>>(x, xh, xl);
    conv_gemm<<<NB * 50, 256, 0, stream>>>(ah, al, xh, xl, scale, bias, out);
}

// Round 4
// 602.796 us; speedup vs baseline: 1.1358x; 1.0248x over previous
//
#include <hip/hip_runtime.h>
#include <hip/hip_bf16.h>
#include <math.h>

// ---------------- problem constants ----------------
#define OC     256
#define IC     128
#define HW     56
#define NB     64
#define KK     1152          // IC*9
#define HP     58            // padded spatial
#define PIX    (HW*HW)       // 3136
#define XPAD_ELEMS ((long)NB*HP*HP*IC)   // 27,557,888
#define A_ELEMS    (OC*KK)               // 294,912

typedef __attribute__((ext_vector_type(8))) short          bf16x8;
typedef __attribute__((ext_vector_type(8))) unsigned short u16x8;
typedef __attribute__((ext_vector_type(4))) float          f32x4;

__device__ __forceinline__ void async_load16(const void* g, void* l) {
    __builtin_amdgcn_global_load_lds(
        (const __attribute__((address_space(1))) void*)g,
        (__attribute__((address_space(3))) void*)l, 16, 0, 0);
}

// bf16 RNE convert (manual, no NaN path needed for our data)
__device__ __forceinline__ unsigned short f2bf(float f) {
    unsigned int u = __float_as_uint(f);
    return (unsigned short)((u + 0x7fffu + ((u >> 16) & 1u)) >> 16);
}
__device__ __forceinline__ float bf2f(unsigned short b) {
    return __uint_as_float(((unsigned int)b) << 16);
}

// XOR-swizzled LDS element offset for logical (row, colgroup q in 0..3):
// physical slot = q ^ ((row>>1)&3) -> 2-way bank aliasing only (free, m136).
__device__ __forceinline__ int lds_off(int row, int q) {
    return row * 32 + (((q ^ (row >> 1)) & 3) << 3);
}

// ---------------- kernel 1: weights + BN constants ----------------
__global__ __launch_bounds__(256) void prep_weights(
        const float* __restrict__ phase, const float* __restrict__ gamma,
        const float* __restrict__ beta,  const float* __restrict__ rmean,
        const float* __restrict__ rvar,
        __hip_bfloat16* __restrict__ ah, __hip_bfloat16* __restrict__ al,
        float* __restrict__ scale, float* __restrict__ bias) {
    int g = blockIdx.x * 256 + threadIdx.x;      // 0 .. 294911
    int oc = g / KK;
    int kk = g - oc * KK;
    int kpos = kk >> 7;          // kh*3+kw
    int ic   = kk & 127;
    int j    = ic * 9 + kpos;    // original flat k = ic*9 + kh*3 + kw
    int pidx = (((oc >> 3) * 144 + (j >> 3)) * 8 + (oc & 7)) * 8 + (j & 7);
    double phi = (double)phase[pidx];
    double c   = cos(phi);
    const double a = 0.987, r = 0.99;
    double num = a*a - 2.0*a*r*c + r*r;
    double den = 1.0 - 2.0*a*r*c + (a*r)*(a*r);
    float t = (float)(num / den);
    unsigned short hb = f2bf(t);
    float hf = bf2f(hb);
    ((unsigned short*)ah)[g] = hb;
    ((unsigned short*)al)[g] = f2bf(t - hf);
    if (g < OC) {
        float inv = gamma[g] / sqrtf(rvar[g] + 1e-5f);
        scale[g] = inv;
        bias[g]  = beta[g] - rmean[g] * inv;
    }
}

// ---------------- kernel 2: pad + transpose + bf16 hi/lo split ----------------
__global__ __launch_bounds__(256) void prep_x(
        const float* __restrict__ x,
        __hip_bfloat16* __restrict__ xh, __hip_bfloat16* __restrict__ xl) {
    int hp  = blockIdx.x;    // 0..57
    int img = blockIdx.y;    // 0..63
    __shared__ float tile[IC * 57];   // [ic][w], stride 57
    int t = threadIdx.x;
    bool border = (hp == 0) || (hp == HP - 1);
    if (!border) {
        int h = hp - 1;
        const float* src = x + (long)img * IC * PIX + h * HW;
#pragma unroll
        for (int i = 0; i < 7; ++i) {            // 128*14 float4 = 1792
            int idx = i * 256 + t;
            int ic  = idx / 14;
            int w4  = (idx - ic * 14) * 4;
            float4 v = *(const float4*)&src[(long)ic * PIX + w4];
            tile[ic * 57 + w4 + 0] = v.x;
            tile[ic * 57 + w4 + 1] = v.y;
            tile[ic * 57 + w4 + 2] = v.z;
            tile[ic * 57 + w4 + 3] = v.w;
        }
    }
    __syncthreads();
    long base = ((long)(img * HP + hp)) * HP * IC;
#pragma unroll
    for (int i = 0; i < 4; ++i) {                // 58*16 = 928 vec-tasks
        int v = i * 256 + t;
        if (v < 928) {
            int icg = v & 15;                    // 8 ic per task
            int wp  = v >> 4;                    // 0..57
            bool inw = !border && wp >= 1 && wp <= HW;
            u16x8 hv, lv;
#pragma unroll
            for (int j = 0; j < 8; ++j) {
                float f = inw ? tile[(icg * 8 + j) * 57 + (wp - 1)] : 0.f;
                unsigned short hb = f2bf(f);
                hv[j] = hb;
                lv[j] = f2bf(f - bf2f(hb));
            }
            long o = base + wp * IC + icg * 8;
            *(u16x8*)&((unsigned short*)xh)[o] = hv;
            *(u16x8*)&((unsigned short*)xl)[o] = lv;
        }
    }
}

// ---------------- kernel 3: implicit GEMM conv + BN + ReLU6 ----------------
// LDS double-buffer + REGISTER fragment double-buffer:
//   per chunk: sync -> issue staging(c+2) -> ds_read frags(c+1) -> MFMA(c)
// MFMAs never depend on in-flight ds_reads -> LDS reads issue in MFMA shadow.
__global__ __launch_bounds__(256, 2) void conv_gemm(
        const __hip_bfloat16* __restrict__ ah, const __hip_bfloat16* __restrict__ al,
        const __hip_bfloat16* __restrict__ xh, const __hip_bfloat16* __restrict__ xl,
        const float* __restrict__ scale, const float* __restrict__ bias,
        float* __restrict__ out) {
    __shared__ __hip_bfloat16 sAh0[4096], sAl0[4096], sBh0[4096], sBl0[4096];
    __shared__ __hip_bfloat16 sAh1[4096], sAl1[4096], sBh1[4096], sBl1[4096];

    int bid = blockIdx.x;
    int img = bid / 50;
    int rem = bid - img * 50;
    int mt  = rem >> 1;      // 0..24  pixel tile
    int ot  = rem & 1;       // oc tile

    int t    = threadIdx.x;
    int lane = t & 63;
    int wave = t >> 6;
    int wm   = wave & 1;     // oc half (64)
    int wn   = wave >> 1;    // pixel half (64)

    int row0 = t >> 2;
    int col0 = (((t & 3) ^ ((t >> 3) & 3))) << 3;

    const __hip_bfloat16* pah0 = ah + (long)(ot * 128 + row0) * KK + col0;
    const __hip_bfloat16* pah1 = pah0 + (long)64 * KK;
    const __hip_bfloat16* pal0 = al + (long)(ot * 128 + row0) * KK + col0;
    const __hip_bfloat16* pal1 = pal0 + (long)64 * KK;

    int m0 = mt * 128 + row0;      if (m0 > PIX - 1) m0 = PIX - 1;
    int m1 = mt * 128 + row0 + 64; if (m1 > PIX - 1) m1 = PIX - 1;
    int h0 = m0 / HW, w0 = m0 - h0 * HW;
    int h1 = m1 / HW, w1 = m1 - h1 * HW;
    const __hip_bfloat16* pxh0 = xh + (long)((img * HP + h0) * HP + w0) * IC + col0;
    const __hip_bfloat16* pxh1 = xh + (long)((img * HP + h1) * HP + w1) * IC + col0;
    const __hip_bfloat16* pxl0 = xl + (long)((img * HP + h0) * HP + w0) * IC + col0;
    const __hip_bfloat16* pxl1 = xl + (long)((img * HP + h1) * HP + w1) * IC + col0;

    int ar[4], br[4];
#pragma unroll
    for (int f = 0; f < 4; ++f) {
        ar[f] = lds_off(wm * 64 + f * 16 + (lane & 15), lane >> 4);
        br[f] = lds_off(wn * 64 + f * 16 + (lane & 15), lane >> 4);
    }

    f32x4 acc[4][4];
#pragma unroll
    for (int i = 0; i < 4; ++i)
#pragma unroll
        for (int jj = 0; jj < 4; ++jj) acc[i][jj] = (f32x4){0.f, 0.f, 0.f, 0.f};

    // two register fragment sets
    bf16x8 aH0[4], aL0[4], bH0[4], bL0[4];
    bf16x8 aH1[4], aL1[4], bH1[4], bL1[4];

#define ISSUE(ci, SAH, SAL, SBH, SBL)                                          \
    {                                                                           \
        int bs = 32 * (ci) + ((ci) >= 12 ? 7040 : 0) + ((ci) >= 24 ? 7040 : 0); \
        long a0 = (long)(ci) * 32;                                              \
        async_load16(pah0 + a0, &SAH[t * 8]);                                   \
        async_load16(pah1 + a0, &SAH[2048 + t * 8]);                            \
        async_load16(pal0 + a0, &SAL[t * 8]);                                   \
        async_load16(pal1 + a0, &SAL[2048 + t * 8]);                            \
        async_load16(pxh0 + bs, &SBH[t * 8]);                                   \
        async_load16(pxh1 + bs, &SBH[2048 + t * 8]);                            \
        async_load16(pxl0 + bs, &SBL[t * 8]);                                   \
        async_load16(pxl1 + bs, &SBL[2048 + t * 8]);                            \
    }

#define READF(AH, AL, BH, BL, SAH, SAL, SBH, SBL)                               \
    {                                                                           \
        _Pragma("unroll")                                                       \
        for (int f = 0; f < 4; ++f) {                                           \
            AH[f] = *(const bf16x8*)&SAH[ar[f]];                                \
            AL[f] = *(const bf16x8*)&SAL[ar[f]];                                \
            BH[f] = *(const bf16x8*)&SBH[br[f]];                                \
            BL[f] = *(const bf16x8*)&SBL[br[f]];                                \
        }                                                                       \
    }

#define MFMAS(AH, AL, BH, BL)                                                   \
    {                                                                           \
        _Pragma("unroll")                                                       \
        for (int fm = 0; fm < 4; ++fm)                                          \
            _Pragma("unroll")                                                   \
            for (int fn = 0; fn < 4; ++fn) {                                    \
                acc[fm][fn] = __builtin_amdgcn_mfma_f32_16x16x32_bf16(AL[fm], BH[fn], acc[fm][fn], 0, 0, 0); \
                acc[fm][fn] = __builtin_amdgcn_mfma_f32_16x16x32_bf16(AH[fm], BL[fn], acc[fm][fn], 0, 0, 0); \
                acc[fm][fn] = __builtin_amdgcn_mfma_f32_16x16x32_bf16(AH[fm], BH[fn], acc[fm][fn], 0, 0, 0); \
            }                                                                   \
    }

    // prologue: stage 0, drain, stage 1, read frags(0)
    ISSUE(0, sAh0, sAl0, sBh0, sBl0);
    __syncthreads();
    ISSUE(1, sAh1, sAl1, sBh1, sBl1);
    READF(aH0, aL0, bH0, bL0, sAh0, sAl0, sBh0, sBl0);

#pragma unroll 1
    for (int cc = 0; cc < 18; ++cc) {
        int c = cc * 2;
        // iter c: frags(c) in set0; staging(c+1) in flight -> buf1
        __syncthreads();                                   // drains staging(c+1) + frag reads(c)
        if (c + 2 < 36) ISSUE(c + 2, sAh0, sAl0, sBh0, sBl0);
        READF(aH1, aL1, bH1, bL1, sAh1, sAl1, sBh1, sBl1); // frags(c+1)
        MFMAS(aH0, aL0, bH0, bL0);                         // chunk c
        // iter c+1: frags(c+1) in set1; staging(c+2) in flight -> buf0
        __syncthreads();
        if (c + 3 < 36) ISSUE(c + 3, sAh1, sAl1, sBh1, sBl1);
        if (c + 2 < 36) READF(aH0, aL0, bH0, bL0, sAh0, sAl0, sBh0, sBl0);
        MFMAS(aH1, aL1, bH1, bL1);                         // chunk c+1
    }
#undef ISSUE
#undef READF
#undef MFMAS

    // epilogue: BN (eval) + ReLU6, store fp32
    int pixc = mt * 128 + wn * 64 + (lane & 15);
    int occ0 = ot * 128 + wm * 64 + ((lane >> 4) << 2);
#pragma unroll
    for (int fm = 0; fm < 4; ++fm) {
#pragma unroll
        for (int r = 0; r < 4; ++r) {
            int oc = occ0 + fm * 16 + r;
            float sc = scale[oc], bi = bias[oc];
            long obase = ((long)(img * OC + oc)) * PIX;
#pragma unroll
            for (int fn = 0; fn < 4; ++fn) {
                int pix = pixc + fn * 16;
                if (pix < PIX) {
                    float v = acc[fm][fn][r] * sc + bi;
                    v = fminf(fmaxf(v, 0.f), 6.f);
                    out[obase + pix] = v;
                }
            }
        }
    }
}

// ---------------- launch ----------------
extern "C" void kernel_launch(void* const* d_in, const int* in_sizes, int n_in,
                              void* d_out, int out_size, void* d_ws, size_t ws_size,
                              hipStream_t stream) {
    const float* x     = (const float*)d_in[0];
    const float* phase = (const float*)d_in[1];
    const float* gamma = (const float*)d_in[2];
    const float* beta  = (const float*)d_in[3];
    const float* rmean = (const float*)d_in[4];
    const float* rvar  = (const float*)d_in[5];
    float* out = (float*)d_out;

    __hip_bfloat16* xh = (__hip_bfloat16*)d_ws;
    __hip_bfloat16* xl = xh + XPAD_ELEMS;
    __hip_bfloat16* ah = xl + XPAD_ELEMS;
    __hip_bfloat16* al = ah + A_ELEMS;
    float* scale = (float*)(al + A_ELEMS);
    float* bias  = scale + OC;

    prep_weights<<<A_ELEMS / 256, 256, 0, stream>>>(phase, gamma, beta, rmean, rvar,
                                                    ah, al, scale, bias);
    prep_x<<<dim3(HP, NB), 256, 0, stream>>>(x, xh, xl);
    conv_gemm<<<NB * 50, 256, 0, stream>>>(ah, al, xh, xl, scale, bias, out);
}